// Round 8
// baseline (316.150 us; speedup 1.0000x reference)
//
#include <hip/hip_runtime.h>
#include <hip/hip_bf16.h>
#include <math.h>

typedef __attribute__((ext_vector_type(8))) short bf16x8;
typedef __attribute__((ext_vector_type(4))) float f32x4;

#define NSAMP  128000
#define TFR    501
#define NFR    32064       // 64*501 frames per signal
#define FPOW   257
#define NF     257
#define B_SZ   64
#define CHUNKT 32
#define NCH    16
#define EPS_F  1.1920928955078125e-07f

#define SEG    16640       // 64*256 + 256 samples per 64-frame chunk
#define SEGB   33280       // SEG * 2 bytes (bf16)

// ---- basis, layout [st 0..7][col 0..511][k 0..63] bf16 -----------------
// col = (bin>>4)*32 + isIm*16 + (bin&15); col 16 (dead im of DC) = Nyquist.
__global__ __launch_bounds__(256)
void build_basis(unsigned short* __restrict__ Bt) {
    int col = blockIdx.x;
    int g = col >> 5, o = col & 15;
    int isIm = (col >> 4) & 1;
    int bin = g * 16 + o;
    for (int k = threadIdx.x; k < 512; k += 256) {
        float w = sinf((float)k * (float)(M_PI / 512.0));   // sqrt-hann
        float v;
        if (col == 16) {
            v = w * ((k & 1) ? -1.f : 1.f);
        } else {
            int mm = (bin * k) & 511;
            float th = (float)mm * (float)(2.0 * M_PI / 512.0);
            v = w * (isIm ? -sinf(th) : cosf(th));
        }
        __hip_bfloat16 h = __float2bfloat16(v);
        Bt[((size_t)(k >> 6) * 512 + col) * 64 + (k & 63)] =
            *reinterpret_cast<unsigned short*>(&h);
    }
}

// ---- MFMA DFT GEMM v8: B direct from L2, barrier-free K-loop ------------
// grid (8 mchunk, 64 b, 2 s) = 1024 blocks, block 512 (8 waves, 1M x 8N).
// Block tile 64 rows x 512 cols; wave tile 64x64 (acc[4][4] = 64 AGPR).
// A: 64-frame bf16 segment in LDS (33KB) -> ~4 blocks/CU.
// B: 512KB basis is L2-resident (every block reads it) -> per-step frags
//    loaded straight to registers with 1-step prefetch. No K-loop barriers.
__global__ __launch_bounds__(512, 4)
void dft_gemm(const float* __restrict__ sig,
              const float* __restrict__ intf,
              const unsigned short* __restrict__ Bt,
              float* __restrict__ powo)
{
    __shared__ char As[SEGB];

    const int mchunk = blockIdx.x, b = blockIdx.y, s = blockIdx.z;
    const int tid = threadIdx.x, lane = tid & 63, wn = tid >> 6;
    const int lq = lane >> 4, ll = lane & 15;
    const float* x = (s == 0 ? intf : sig) + (size_t)b * NSAMP;
    const int tbase = mchunk * 16384 - 256;

    // ---- A staging: contiguous segment, float4, bf16, addr-XOR swizzle ----
    {
        const int jlo = (tbase < 0) ? -tbase : 0;
        const int jhi = (tbase + SEG > NSAMP) ? (NSAMP - tbase) : SEG;
        for (int i = tid; i < SEG / 4; i += 512) {
            int j = i * 4;
            float f0, f1, f2, f3;
            if (j >= jlo && j + 4 <= jhi) {
                float4 v = *(const float4*)(x + tbase + j);
                f0 = v.x; f1 = v.y; f2 = v.z; f3 = v.w;
            } else {
                int p0 = tbase + j;
                int pp[4];
                #pragma unroll
                for (int e = 0; e < 4; ++e) {
                    int p = p0 + e;
                    if (p < 0) p = -p;
                    if (p >= NSAMP) p = 2 * NSAMP - 2 - p;
                    pp[e] = p;
                }
                f0 = x[pp[0]]; f1 = x[pp[1]]; f2 = x[pp[2]]; f3 = x[pp[3]];
            }
            unsigned short h[4];
            __hip_bfloat16 t0 = __float2bfloat16(f0); h[0] = *(unsigned short*)&t0;
            __hip_bfloat16 t1 = __float2bfloat16(f1); h[1] = *(unsigned short*)&t1;
            __hip_bfloat16 t2 = __float2bfloat16(f2); h[2] = *(unsigned short*)&t2;
            __hip_bfloat16 t3 = __float2bfloat16(f3); h[3] = *(unsigned short*)&t3;
            unsigned long long pk =
                (unsigned long long)h[0] | ((unsigned long long)h[1] << 16) |
                ((unsigned long long)h[2] << 32) | ((unsigned long long)h[3] << 48);
            int a = i * 8;
            a ^= ((a >> 9) & 7) << 4;
            *(unsigned long long*)(As + a) = pk;
        }
    }
    __syncthreads();    // the ONLY barrier: A ready; K-loop is free-running

    f32x4 acc[4][4];
    #pragma unroll
    for (int i = 0; i < 4; ++i)
        #pragma unroll
        for (int j = 0; j < 4; ++j) acc[i][j] = 0;

    // per-lane base into basis: col = wn*64 + nf*16 + ll, k-chunk lq
    const char* bbase = (const char*)Bt + (size_t)(wn * 64 + ll) * 128 + lq * 16;

    auto loadB = [&](int st, bf16x8 (&dst)[8]) {
        const char* p = bbase + (size_t)st * 65536;
        #pragma unroll
        for (int nf = 0; nf < 4; ++nf) {
            dst[nf * 2]     = *(const bf16x8*)(p + nf * 2048);
            dst[nf * 2 + 1] = *(const bf16x8*)(p + nf * 2048 + 64);
        }
    };

    auto step = [&](int st, bf16x8 (&cur)[8], bf16x8 (&nxt)[8]) {
        bf16x8 af[4][2];
        #pragma unroll
        for (int mf = 0; mf < 4; ++mf)
            #pragma unroll
            for (int kb = 0; kb < 2; ++kb) {
                int a = (mf * 16 + ll) * 512 + st * 128 + kb * 64 + lq * 16;
                a ^= ((a >> 9) & 7) << 4;
                af[mf][kb] = *(const bf16x8*)(As + a);
            }
        if (st < 7) loadB(st + 1, nxt);    // prefetch hides under MFMAs
        __builtin_amdgcn_s_setprio(1);
        #pragma unroll
        for (int kb = 0; kb < 2; ++kb)
            #pragma unroll
            for (int mf = 0; mf < 4; ++mf)
                #pragma unroll
                for (int nf = 0; nf < 4; ++nf)
                    acc[mf][nf] = __builtin_amdgcn_mfma_f32_16x16x32_bf16(
                        af[mf][kb], cur[nf * 2 + kb], acc[mf][nf], 0, 0, 0);
        __builtin_amdgcn_s_setprio(0);
    };

    bf16x8 bA[8], bB[8];
    loadB(0, bA);
    #pragma unroll
    for (int st2 = 0; st2 < 8; st2 += 2) {
        step(st2,     bA, bB);
        step(st2 + 1, bB, bA);
    }

    // ---- epilogue: power = re^2 + im^2 ----
    const size_t rowbase = ((size_t)(s * 64 + b)) * TFR;
    #pragma unroll
    for (int mf = 0; mf < 4; ++mf) {
        #pragma unroll
        for (int p = 0; p < 2; ++p) {
            f32x4 re = acc[mf][2 * p], im = acc[mf][2 * p + 1];
            int g2 = wn * 2 + p;
            int bin = g2 * 16 + ll;
            bool nyq = (g2 == 0) && (ll == 0);
            #pragma unroll
            for (int j = 0; j < 4; ++j) {
                int rl = mchunk * 64 + mf * 16 + lq * 4 + j;
                if (rl < TFR) {
                    float pr = re[j] * re[j];
                    float pi = im[j] * im[j];
                    float* po = powo + (rowbase + rl) * FPOW;
                    po[bin] = nyq ? pr : (pr + pi);
                    if (nyq) po[256] = pi;
                }
            }
        }
    }
}

// ---- warm-up: batched loads then fmaf chain -----------------------------
template<int W>
__device__ __forceinline__ float warm_sum(const float* __restrict__ nrow,
                                          int ts, float alpha, float oma) {
    float q[W + 1];
    #pragma unroll
    for (int i = 0; i <= W; ++i) q[i] = nrow[(size_t)(ts + i) * FPOW];
    float v = q[0];
    #pragma unroll
    for (int i = 1; i <= W; ++i) v = fmaf(alpha, v, oma * q[i]);
    return v;
}

// ---- chunked IIR scan + SPP + MSE, pipelined & unrolled ----------------
__global__ __launch_bounds__(256, 4)
void spp_loss_kernel(const float* __restrict__ noiseP,
                     const float* __restrict__ noisyP,
                     const float* __restrict__ est,
                     float* __restrict__ out,
                     float alpha)
{
    const double XI = 31.622776601683793;
    const float RATIO = (float)(1.0 + XI);
    const float COEF  = (float)(XI / (1.0 + XI));
    const float INVN  = (float)(1.0 / ((double)B_SZ * NF * TFR));

    int tid = blockIdx.x * blockDim.x + threadIdx.x;
    int f   = tid % NF;
    int rem = tid / NF;
    int c   = rem & (NCH - 1);
    int b   = rem >> 4;

    float local = 0.f;
    if (b < B_SZ) {
        const int t0   = c * CHUNKT;
        const int tend = min(TFR, t0 + CHUNKT);
        const float* nrow = noiseP + (size_t)b * TFR * FPOW + f;
        const float* yrow = noisyP + (size_t)b * TFR * FPOW + f;
        const float* erow = est + ((size_t)b * NF + f) * TFR;
        const float oma = 1.f - alpha;

        float v;
        if (t0 == 0)            v = nrow[0];
        else if (t0 == CHUNKT)  v = warm_sum<CHUNKT>(nrow, 0, alpha, oma);
        else                    v = warm_sum<48>(nrow, t0 - 48, alpha, oma);

        {
            float np = yrow[(size_t)t0 * FPOW];
            float e0 = erow[t0];
            float expo = -np / (v + EPS_F) * COEF;
            float spp  = 1.f / fmaf(RATIO, __expf(expo), 1.f);
            float d = e0 - spp;
            local = fmaf(d, d, local);
        }
        #pragma unroll
        for (int h = 0; h < 2; ++h) {
            float qn[16], qy[16], qe[16];
            #pragma unroll
            for (int i = 0; i < 16; ++i) {
                int t = min(t0 + h * 16 + i + 1, TFR - 1);
                qn[i] = nrow[(size_t)t * FPOW];
                qy[i] = yrow[(size_t)t * FPOW];
                qe[i] = erow[t];
            }
            #pragma unroll
            for (int i = 0; i < 16; ++i) {
                int t = t0 + h * 16 + i + 1;
                v = fmaf(alpha, v, oma * qn[i]);
                if (t < tend) {
                    float expo = -qy[i] / (v + EPS_F) * COEF;
                    float spp  = 1.f / fmaf(RATIO, __expf(expo), 1.f);
                    float d = qe[i] - spp;
                    local = fmaf(d, d, local);
                }
            }
        }
    }

    for (int off = 32; off > 0; off >>= 1)
        local += __shfl_down(local, off);
    __shared__ float wsum[4];
    if ((threadIdx.x & 63) == 0) wsum[threadIdx.x >> 6] = local;
    __syncthreads();
    if (threadIdx.x == 0) {
        float ssum = (wsum[0] + wsum[1]) + (wsum[2] + wsum[3]);
        atomicAdd(out, ssum * INVN);
    }
}

extern "C" void kernel_launch(void* const* d_in, const int* in_sizes, int n_in,
                              void* d_out, int out_size, void* d_ws, size_t ws_size,
                              hipStream_t stream) {
    const float* est  = (const float*)d_in[0];   // spp_estimate (B,1,F,T)
    const float* sig  = (const float*)d_in[1];   // input_sig    (B,1,N)
    const float* intf = (const float*)d_in[2];   // interference (B,1,N)

    unsigned short* Bt = (unsigned short*)d_ws;                 // 512 KB basis
    float* powp = (float*)((char*)d_ws + (size_t)8 * 512 * 64 * 2);

    hipLaunchKernelGGL(build_basis, dim3(512), dim3(256), 0, stream, Bt);
    hipMemsetAsync(d_out, 0, sizeof(float), stream);

    dim3 gG(8, 64, 2);
    hipLaunchKernelGGL(dft_gemm, gG, dim3(512), 0, stream,
                       sig, intf, Bt, powp);

    const double alpha_d = exp(-((double)256) / (16000.0 * 0.072));
    const float* noiseP = powp;                          // s=0: interference
    const float* noisyP = powp + (size_t)NFR * FPOW;     // s=1: input_sig
    dim3 gB((B_SZ * NCH * NF + 255) / 256);
    hipLaunchKernelGGL(spp_loss_kernel, gB, dim3(256), 0, stream,
                       noiseP, noisyP, est, (float*)d_out, (float)alpha_d);
}

// Round 9
// 112.879 us; speedup vs baseline: 2.8008x; 2.8008x over previous
//
#include <hip/hip_runtime.h>
#include <hip/hip_bf16.h>
#include <math.h>

typedef __attribute__((ext_vector_type(8))) short bf16x8;
typedef __attribute__((ext_vector_type(4))) float f32x4;

#define NSAMP  128000
#define TFR    501
#define NFR    32064       // 64*501 frames per signal
#define FPOW   257
#define NF     257
#define B_SZ   64
#define CHUNKT 32
#define NCH    16
#define EPS_F  1.1920928955078125e-07f

#define SEG    16640       // 64*256 + 256 samples per 64-frame chunk
#define SEGB   33280       // SEG * 2 bytes (bf16)
#define BBUFB  32768       // 256 cols * 128 B, single buffer, one (nt,st) tile
#define LDS_TOTAL (SEGB + BBUFB)   // 66048 B -> 2 blocks/CU

// ---- basis, layout [st 0..7][col 0..511][k 0..63] bf16 -----------------
// col = (bin>>4)*32 + isIm*16 + (bin&15); col 16 (dead im of DC) = Nyquist.
__global__ __launch_bounds__(256)
void build_basis(unsigned short* __restrict__ Bt) {
    int col = blockIdx.x;
    int g = col >> 5, o = col & 15;
    int isIm = (col >> 4) & 1;
    int bin = g * 16 + o;
    for (int k = threadIdx.x; k < 512; k += 256) {
        float w = sinf((float)k * (float)(M_PI / 512.0));   // sqrt-hann
        float v;
        if (col == 16) {
            v = w * ((k & 1) ? -1.f : 1.f);
        } else {
            int mm = (bin * k) & 511;
            float th = (float)mm * (float)(2.0 * M_PI / 512.0);
            v = w * (isIm ? -sinf(th) : cosf(th));
        }
        __hip_bfloat16 h = __float2bfloat16(v);
        Bt[((size_t)(k >> 6) * 512 + col) * 64 + (k & 63)] =
            *reinterpret_cast<unsigned short*>(&h);
    }
}

// ---- MFMA DFT GEMM v9: 2 blocks/CU, 4-wave blocks, single-buf B ---------
// grid (8 mchunk, 64 b, 2 s) = 1024 blocks, block 256 (4 waves over N).
// Block tile 64 rows x 256 cols x K512, nt in {0,1} inner loop (A reused).
// LDS 66KB = A seg (33KB, swizzled bf16) + one 32KB B tile -> 2 blocks/CU,
// so barrier bubbles in one block are covered by the other block's waves.
__global__ __launch_bounds__(256, 2)
void dft_gemm(const float* __restrict__ sig,
              const float* __restrict__ intf,
              const unsigned short* __restrict__ Bt,
              float* __restrict__ powo)
{
    extern __shared__ char smem[];
    char* As = smem;
    char* Bl = smem + SEGB;

    const int mchunk = blockIdx.x, b = blockIdx.y, s = blockIdx.z;
    const int tid = threadIdx.x, lane = tid & 63, wn = tid >> 6;  // 4 waves
    const int lq = lane >> 4, ll = lane & 15;
    const float* x = (s == 0 ? intf : sig) + (size_t)b * NSAMP;
    const int tbase = mchunk * 16384 - 256;

    // stage 256col x 64k B tile for phase q=(nt,st). Dest linear (wave-uniform
    // base + lane*16), source pre-inverse-swizzled (same involution as reads).
    auto stageB = [&](int q) {
        const int nt = q >> 3, st = q & 7;
        const char* gb = (const char*)Bt + (size_t)(st * 512 + nt * 256) * 128;
        #pragma unroll
        for (int i = 0; i < 8; ++i) {
            int o = i * 4096 + tid * 16;
            int src = o ^ (((o >> 7) & 7) << 4);
            __builtin_amdgcn_global_load_lds(
                (const __attribute__((address_space(1))) void*)(gb + src),
                (__attribute__((address_space(3))) void*)(Bl + o), 16, 0, 0);
        }
    };

    stageB(0);

    // ---- A staging: contiguous segment, float4, bf16, addr-XOR swizzle ----
    {
        const int jlo = (tbase < 0) ? -tbase : 0;
        const int jhi = (tbase + SEG > NSAMP) ? (NSAMP - tbase) : SEG;
        for (int i = tid; i < SEG / 4; i += 256) {
            int j = i * 4;
            float f0, f1, f2, f3;
            if (j >= jlo && j + 4 <= jhi) {
                float4 v = *(const float4*)(x + tbase + j);
                f0 = v.x; f1 = v.y; f2 = v.z; f3 = v.w;
            } else {
                int p0 = tbase + j;
                int pp[4];
                #pragma unroll
                for (int e = 0; e < 4; ++e) {
                    int p = p0 + e;
                    if (p < 0) p = -p;
                    if (p >= NSAMP) p = 2 * NSAMP - 2 - p;
                    pp[e] = p;
                }
                f0 = x[pp[0]]; f1 = x[pp[1]]; f2 = x[pp[2]]; f3 = x[pp[3]];
            }
            unsigned short h[4];
            __hip_bfloat16 t0 = __float2bfloat16(f0); h[0] = *(unsigned short*)&t0;
            __hip_bfloat16 t1 = __float2bfloat16(f1); h[1] = *(unsigned short*)&t1;
            __hip_bfloat16 t2 = __float2bfloat16(f2); h[2] = *(unsigned short*)&t2;
            __hip_bfloat16 t3 = __float2bfloat16(f3); h[3] = *(unsigned short*)&t3;
            unsigned long long pk =
                (unsigned long long)h[0] | ((unsigned long long)h[1] << 16) |
                ((unsigned long long)h[2] << 32) | ((unsigned long long)h[3] << 48);
            int a = i * 8;
            a ^= ((a >> 9) & 7) << 4;
            *(unsigned long long*)(As + a) = pk;
        }
    }
    asm volatile("s_waitcnt vmcnt(0)" ::: "memory");
    __syncthreads();   // A ready + B tile 0 landed

    f32x4 acc[4][4];
    #pragma unroll
    for (int i = 0; i < 4; ++i)
        #pragma unroll
        for (int j = 0; j < 4; ++j) acc[i][j] = 0;

    const size_t rowbase = ((size_t)(s * 64 + b)) * TFR;

    for (int q = 0; q < 16; ++q) {
        const int st = q & 7;
        bf16x8 af[4][2], bfr[4][2];
        // ---- ds_read all fragments for this phase ----
        #pragma unroll
        for (int mf = 0; mf < 4; ++mf)
            #pragma unroll
            for (int kb = 0; kb < 2; ++kb) {
                int a = (mf * 16 + ll) * 512 + st * 128 + kb * 64 + lq * 16;
                a ^= ((a >> 9) & 7) << 4;
                af[mf][kb] = *(const bf16x8*)(As + a);
            }
        #pragma unroll
        for (int nf = 0; nf < 4; ++nf)
            #pragma unroll
            for (int kb = 0; kb < 2; ++kb) {
                int bo = (wn * 64 + nf * 16 + ll) * 128 + kb * 64 + lq * 16;
                bo ^= ((bo >> 7) & 7) << 4;
                bfr[nf][kb] = *(const bf16x8*)(Bl + bo);
            }
        // ---- kb0 MFMA cluster ----
        __builtin_amdgcn_s_setprio(1);
        #pragma unroll
        for (int mf = 0; mf < 4; ++mf)
            #pragma unroll
            for (int nf = 0; nf < 4; ++nf)
                acc[mf][nf] = __builtin_amdgcn_mfma_f32_16x16x32_bf16(
                    af[mf][0], bfr[nf][0], acc[mf][nf], 0, 0, 0);
        __builtin_amdgcn_s_setprio(0);
        __syncthreads();                   // everyone's B reads done
        if (q < 15) stageB(q + 1);         // refill; hides under kb1
        __builtin_amdgcn_s_setprio(1);
        #pragma unroll
        for (int mf = 0; mf < 4; ++mf)
            #pragma unroll
            for (int nf = 0; nf < 4; ++nf)
                acc[mf][nf] = __builtin_amdgcn_mfma_f32_16x16x32_bf16(
                    af[mf][1], bfr[nf][1], acc[mf][nf], 0, 0, 0);
        __builtin_amdgcn_s_setprio(0);
        asm volatile("s_waitcnt vmcnt(0)" ::: "memory");
        __syncthreads();                   // next tile landed

        if (st == 7) {
            // ---- epilogue for this nt: power = re^2 + im^2 ----
            const int nt = q >> 3;
            #pragma unroll
            for (int mf = 0; mf < 4; ++mf) {
                #pragma unroll
                for (int u = 0; u < 2; ++u) {
                    f32x4 re = acc[mf][2 * u], im = acc[mf][2 * u + 1];
                    int gbin = nt * 8 + wn * 2 + u;
                    int bin = gbin * 16 + ll;
                    bool nyq = (gbin == 0) && (ll == 0);
                    #pragma unroll
                    for (int j = 0; j < 4; ++j) {
                        int rl = mchunk * 64 + mf * 16 + lq * 4 + j;
                        if (rl < TFR) {
                            float pr = re[j] * re[j];
                            float pi = im[j] * im[j];
                            float* po = powo + (rowbase + rl) * FPOW;
                            po[bin] = nyq ? pr : (pr + pi);
                            if (nyq) po[256] = pi;
                        }
                    }
                }
            }
            #pragma unroll
            for (int i = 0; i < 4; ++i)
                #pragma unroll
                for (int j = 0; j < 4; ++j) acc[i][j] = 0;
        }
    }
}

// ---- warm-up: batched loads then fmaf chain -----------------------------
template<int W>
__device__ __forceinline__ float warm_sum(const float* __restrict__ nrow,
                                          int ts, float alpha, float oma) {
    float q[W + 1];
    #pragma unroll
    for (int i = 0; i <= W; ++i) q[i] = nrow[(size_t)(ts + i) * FPOW];
    float v = q[0];
    #pragma unroll
    for (int i = 1; i <= W; ++i) v = fmaf(alpha, v, oma * q[i]);
    return v;
}

// ---- chunked IIR scan + SPP + MSE, pipelined & unrolled ----------------
__global__ __launch_bounds__(256, 4)
void spp_loss_kernel(const float* __restrict__ noiseP,
                     const float* __restrict__ noisyP,
                     const float* __restrict__ est,
                     float* __restrict__ out,
                     float alpha)
{
    const double XI = 31.622776601683793;
    const float RATIO = (float)(1.0 + XI);
    const float COEF  = (float)(XI / (1.0 + XI));
    const float INVN  = (float)(1.0 / ((double)B_SZ * NF * TFR));

    int tid = blockIdx.x * blockDim.x + threadIdx.x;
    int f   = tid % NF;
    int rem = tid / NF;
    int c   = rem & (NCH - 1);
    int b   = rem >> 4;

    float local = 0.f;
    if (b < B_SZ) {
        const int t0   = c * CHUNKT;
        const int tend = min(TFR, t0 + CHUNKT);
        const float* nrow = noiseP + (size_t)b * TFR * FPOW + f;
        const float* yrow = noisyP + (size_t)b * TFR * FPOW + f;
        const float* erow = est + ((size_t)b * NF + f) * TFR;
        const float oma = 1.f - alpha;

        float v;
        if (t0 == 0)            v = nrow[0];
        else if (t0 == CHUNKT)  v = warm_sum<CHUNKT>(nrow, 0, alpha, oma);
        else                    v = warm_sum<48>(nrow, t0 - 48, alpha, oma);

        {
            float np = yrow[(size_t)t0 * FPOW];
            float e0 = erow[t0];
            float expo = -np / (v + EPS_F) * COEF;
            float spp  = 1.f / fmaf(RATIO, __expf(expo), 1.f);
            float d = e0 - spp;
            local = fmaf(d, d, local);
        }
        #pragma unroll
        for (int h = 0; h < 2; ++h) {
            float qn[16], qy[16], qe[16];
            #pragma unroll
            for (int i = 0; i < 16; ++i) {
                int t = min(t0 + h * 16 + i + 1, TFR - 1);
                qn[i] = nrow[(size_t)t * FPOW];
                qy[i] = yrow[(size_t)t * FPOW];
                qe[i] = erow[t];
            }
            #pragma unroll
            for (int i = 0; i < 16; ++i) {
                int t = t0 + h * 16 + i + 1;
                v = fmaf(alpha, v, oma * qn[i]);
                if (t < tend) {
                    float expo = -qy[i] / (v + EPS_F) * COEF;
                    float spp  = 1.f / fmaf(RATIO, __expf(expo), 1.f);
                    float d = qe[i] - spp;
                    local = fmaf(d, d, local);
                }
            }
        }
    }

    for (int off = 32; off > 0; off >>= 1)
        local += __shfl_down(local, off);
    __shared__ float wsum[4];
    if ((threadIdx.x & 63) == 0) wsum[threadIdx.x >> 6] = local;
    __syncthreads();
    if (threadIdx.x == 0) {
        float ssum = (wsum[0] + wsum[1]) + (wsum[2] + wsum[3]);
        atomicAdd(out, ssum * INVN);
    }
}

extern "C" void kernel_launch(void* const* d_in, const int* in_sizes, int n_in,
                              void* d_out, int out_size, void* d_ws, size_t ws_size,
                              hipStream_t stream) {
    const float* est  = (const float*)d_in[0];   // spp_estimate (B,1,F,T)
    const float* sig  = (const float*)d_in[1];   // input_sig    (B,1,N)
    const float* intf = (const float*)d_in[2];   // interference (B,1,N)

    unsigned short* Bt = (unsigned short*)d_ws;                 // 512 KB basis
    float* powp = (float*)((char*)d_ws + (size_t)8 * 512 * 64 * 2);

    hipLaunchKernelGGL(build_basis, dim3(512), dim3(256), 0, stream, Bt);
    hipMemsetAsync(d_out, 0, sizeof(float), stream);

    hipFuncSetAttribute((const void*)dft_gemm,
                        hipFuncAttributeMaxDynamicSharedMemorySize, LDS_TOTAL);
    dim3 gG(8, 64, 2);
    hipLaunchKernelGGL(dft_gemm, gG, dim3(256), LDS_TOTAL, stream,
                       sig, intf, Bt, powp);

    const double alpha_d = exp(-((double)256) / (16000.0 * 0.072));
    const float* noiseP = powp;                          // s=0: interference
    const float* noisyP = powp + (size_t)NFR * FPOW;     // s=1: input_sig
    dim3 gB((B_SZ * NCH * NF + 255) / 256);
    hipLaunchKernelGGL(spp_loss_kernel, gB, dim3(256), 0, stream,
                       noiseP, noisyP, est, (float*)d_out, (float)alpha_d);
}

// Round 10
// 110.943 us; speedup vs baseline: 2.8497x; 1.0175x over previous
//
#include <hip/hip_runtime.h>
#include <hip/hip_bf16.h>
#include <math.h>

typedef __attribute__((ext_vector_type(8))) short bf16x8;
typedef __attribute__((ext_vector_type(4))) float f32x4;

#define NSAMP  128000
#define TFR    501
#define NFR    32064       // 64*501 frames per signal
#define FPOW   257
#define NF     257
#define B_SZ   64
#define CHUNKT 32
#define NCH    16
#define EPS_F  1.1920928955078125e-07f

#define SEG    16640       // 64*256 + 256 samples per 64-frame chunk
#define SEGB   33280       // SEG * 2 bytes (bf16)
#define BPHB   32768       // 512 cols * 64 B (K=32) per phase, single buffer
#define LDS_TOTAL (SEGB + BPHB)   // 66048 B -> 2 blocks/CU

// ---- basis, layout [ph 0..15][col 0..511][k 0..31] bf16 -----------------
// col = (bin>>4)*32 + isIm*16 + (bin&15); col 16 (dead im of DC) = Nyquist.
__global__ __launch_bounds__(256)
void build_basis(unsigned short* __restrict__ Bt) {
    int col = blockIdx.x;
    int g = col >> 5, o = col & 15;
    int isIm = (col >> 4) & 1;
    int bin = g * 16 + o;
    for (int k = threadIdx.x; k < 512; k += 256) {
        float w = sinf((float)k * (float)(M_PI / 512.0));   // sqrt-hann
        float v;
        if (col == 16) {
            v = w * ((k & 1) ? -1.f : 1.f);
        } else {
            int mm = (bin * k) & 511;
            float th = (float)mm * (float)(2.0 * M_PI / 512.0);
            v = w * (isIm ? -sinf(th) : cosf(th));
        }
        __hip_bfloat16 h = __float2bfloat16(v);
        Bt[((size_t)(k >> 5) * 512 + col) * 32 + (k & 31)] =
            *reinterpret_cast<unsigned short*>(&h);
    }
}

// ---- MFMA DFT GEMM v10: wave tile 64x128, K-phase 32, LDS-read balanced --
// grid (8 mchunk, 64 b, 2 s) = 1024 blocks, block 256 (4 waves over N).
// Block tile 64 rows x 512 cols in ONE pass; per phase: 12 ds_read_b128
// feed 32 MFMAs (0.375 reads/MFMA) -> MFMA pipe binding, not LDS.
// B tile [col][64B]: bank-class residue 4*(ll&1)+lq is uniform -> no swizzle,
// linear staging source. A unchanged (XOR-swizzled raw signal segment).
__global__ __launch_bounds__(256, 2)
void dft_gemm(const float* __restrict__ sig,
              const float* __restrict__ intf,
              const unsigned short* __restrict__ Bt,
              float* __restrict__ powo)
{
    extern __shared__ char smem[];
    char* As = smem;
    char* Bl = smem + SEGB;

    const int mchunk = blockIdx.x, b = blockIdx.y, s = blockIdx.z;
    const int tid = threadIdx.x, lane = tid & 63, wn = tid >> 6;  // 4 waves
    const int lq = lane >> 4, ll = lane & 15;
    const float* x = (s == 0 ? intf : sig) + (size_t)b * NSAMP;
    const int tbase = mchunk * 16384 - 256;

    // stage 512col x 32k B tile for phase ph (32KB), fully linear both sides
    auto stageB = [&](int ph) {
        const char* gb = (const char*)Bt + (size_t)ph * BPHB;
        #pragma unroll
        for (int i = 0; i < 8; ++i) {
            int o = i * 4096 + tid * 16;
            __builtin_amdgcn_global_load_lds(
                (const __attribute__((address_space(1))) void*)(gb + o),
                (__attribute__((address_space(3))) void*)(Bl + o), 16, 0, 0);
        }
    };

    stageB(0);

    // ---- A staging: contiguous segment, float4, bf16, addr-XOR swizzle ----
    {
        const int jlo = (tbase < 0) ? -tbase : 0;
        const int jhi = (tbase + SEG > NSAMP) ? (NSAMP - tbase) : SEG;
        for (int i = tid; i < SEG / 4; i += 256) {
            int j = i * 4;
            float f0, f1, f2, f3;
            if (j >= jlo && j + 4 <= jhi) {
                float4 v = *(const float4*)(x + tbase + j);
                f0 = v.x; f1 = v.y; f2 = v.z; f3 = v.w;
            } else {
                int p0 = tbase + j;
                int pp[4];
                #pragma unroll
                for (int e = 0; e < 4; ++e) {
                    int p = p0 + e;
                    if (p < 0) p = -p;
                    if (p >= NSAMP) p = 2 * NSAMP - 2 - p;
                    pp[e] = p;
                }
                f0 = x[pp[0]]; f1 = x[pp[1]]; f2 = x[pp[2]]; f3 = x[pp[3]];
            }
            unsigned short h[4];
            __hip_bfloat16 t0 = __float2bfloat16(f0); h[0] = *(unsigned short*)&t0;
            __hip_bfloat16 t1 = __float2bfloat16(f1); h[1] = *(unsigned short*)&t1;
            __hip_bfloat16 t2 = __float2bfloat16(f2); h[2] = *(unsigned short*)&t2;
            __hip_bfloat16 t3 = __float2bfloat16(f3); h[3] = *(unsigned short*)&t3;
            unsigned long long pk =
                (unsigned long long)h[0] | ((unsigned long long)h[1] << 16) |
                ((unsigned long long)h[2] << 32) | ((unsigned long long)h[3] << 48);
            int a = i * 8;
            a ^= ((a >> 9) & 7) << 4;
            *(unsigned long long*)(As + a) = pk;
        }
    }
    asm volatile("s_waitcnt vmcnt(0)" ::: "memory");
    __syncthreads();   // A ready + B tile 0 landed

    f32x4 acc[4][8];
    #pragma unroll
    for (int i = 0; i < 4; ++i)
        #pragma unroll
        for (int j = 0; j < 8; ++j) acc[i][j] = 0;

    for (int ph = 0; ph < 16; ++ph) {
        bf16x8 af[4], bfr[8];
        // ---- 12 ds_read_b128: fragments for this 32-K phase ----
        #pragma unroll
        for (int mf = 0; mf < 4; ++mf) {
            int a = (mf * 16 + ll) * 512 + ph * 64 + lq * 16;
            a ^= ((a >> 9) & 7) << 4;
            af[mf] = *(const bf16x8*)(As + a);
        }
        #pragma unroll
        for (int nf = 0; nf < 8; ++nf) {
            int bo = (wn * 128 + nf * 16 + ll) * 64 + lq * 16;
            bfr[nf] = *(const bf16x8*)(Bl + bo);
        }
        __syncthreads();                   // everyone's B reads done; buf free
        if (ph < 15) stageB(ph + 1);       // refill; hides under MFMA cluster
        __builtin_amdgcn_s_setprio(1);
        #pragma unroll
        for (int mf = 0; mf < 4; ++mf)
            #pragma unroll
            for (int nf = 0; nf < 8; ++nf)
                acc[mf][nf] = __builtin_amdgcn_mfma_f32_16x16x32_bf16(
                    af[mf], bfr[nf], acc[mf][nf], 0, 0, 0);
        __builtin_amdgcn_s_setprio(0);
        __syncthreads();                   // vmcnt(0): tile ph+1 landed
    }

    // ---- epilogue: power = re^2 + im^2 ----
    const size_t rowbase = ((size_t)(s * 64 + b)) * TFR;
    #pragma unroll
    for (int mf = 0; mf < 4; ++mf) {
        #pragma unroll
        for (int p = 0; p < 4; ++p) {
            f32x4 re = acc[mf][2 * p], im = acc[mf][2 * p + 1];
            int gbin = wn * 4 + p;
            int bin = gbin * 16 + ll;
            bool nyq = (gbin == 0) && (ll == 0);
            #pragma unroll
            for (int j = 0; j < 4; ++j) {
                int rl = mchunk * 64 + mf * 16 + lq * 4 + j;
                if (rl < TFR) {
                    float pr = re[j] * re[j];
                    float pi = im[j] * im[j];
                    float* po = powo + (rowbase + rl) * FPOW;
                    po[bin] = nyq ? pr : (pr + pi);
                    if (nyq) po[256] = pi;
                }
            }
        }
    }
}

// ---- warm-up: batched loads then fmaf chain -----------------------------
template<int W>
__device__ __forceinline__ float warm_sum(const float* __restrict__ nrow,
                                          int ts, float alpha, float oma) {
    float q[W + 1];
    #pragma unroll
    for (int i = 0; i <= W; ++i) q[i] = nrow[(size_t)(ts + i) * FPOW];
    float v = q[0];
    #pragma unroll
    for (int i = 1; i <= W; ++i) v = fmaf(alpha, v, oma * q[i]);
    return v;
}

// ---- chunked IIR scan + SPP + MSE, pipelined & unrolled ----------------
__global__ __launch_bounds__(256, 4)
void spp_loss_kernel(const float* __restrict__ noiseP,
                     const float* __restrict__ noisyP,
                     const float* __restrict__ est,
                     float* __restrict__ out,
                     float alpha)
{
    const double XI = 31.622776601683793;
    const float RATIO = (float)(1.0 + XI);
    const float COEF  = (float)(XI / (1.0 + XI));
    const float INVN  = (float)(1.0 / ((double)B_SZ * NF * TFR));

    int tid = blockIdx.x * blockDim.x + threadIdx.x;
    int f   = tid % NF;
    int rem = tid / NF;
    int c   = rem & (NCH - 1);
    int b   = rem >> 4;

    float local = 0.f;
    if (b < B_SZ) {
        const int t0   = c * CHUNKT;
        const int tend = min(TFR, t0 + CHUNKT);
        const float* nrow = noiseP + (size_t)b * TFR * FPOW + f;
        const float* yrow = noisyP + (size_t)b * TFR * FPOW + f;
        const float* erow = est + ((size_t)b * NF + f) * TFR;
        const float oma = 1.f - alpha;

        float v;
        if (t0 == 0)            v = nrow[0];
        else if (t0 == CHUNKT)  v = warm_sum<CHUNKT>(nrow, 0, alpha, oma);
        else                    v = warm_sum<48>(nrow, t0 - 48, alpha, oma);

        {
            float np = yrow[(size_t)t0 * FPOW];
            float e0 = erow[t0];
            float expo = -np / (v + EPS_F) * COEF;
            float spp  = 1.f / fmaf(RATIO, __expf(expo), 1.f);
            float d = e0 - spp;
            local = fmaf(d, d, local);
        }
        #pragma unroll
        for (int h = 0; h < 2; ++h) {
            float qn[16], qy[16], qe[16];
            #pragma unroll
            for (int i = 0; i < 16; ++i) {
                int t = min(t0 + h * 16 + i + 1, TFR - 1);
                qn[i] = nrow[(size_t)t * FPOW];
                qy[i] = yrow[(size_t)t * FPOW];
                qe[i] = erow[t];
            }
            #pragma unroll
            for (int i = 0; i < 16; ++i) {
                int t = t0 + h * 16 + i + 1;
                v = fmaf(alpha, v, oma * qn[i]);
                if (t < tend) {
                    float expo = -qy[i] / (v + EPS_F) * COEF;
                    float spp  = 1.f / fmaf(RATIO, __expf(expo), 1.f);
                    float d = qe[i] - spp;
                    local = fmaf(d, d, local);
                }
            }
        }
    }

    for (int off = 32; off > 0; off >>= 1)
        local += __shfl_down(local, off);
    __shared__ float wsum[4];
    if ((threadIdx.x & 63) == 0) wsum[threadIdx.x >> 6] = local;
    __syncthreads();
    if (threadIdx.x == 0) {
        float ssum = (wsum[0] + wsum[1]) + (wsum[2] + wsum[3]);
        atomicAdd(out, ssum * INVN);
    }
}

extern "C" void kernel_launch(void* const* d_in, const int* in_sizes, int n_in,
                              void* d_out, int out_size, void* d_ws, size_t ws_size,
                              hipStream_t stream) {
    const float* est  = (const float*)d_in[0];   // spp_estimate (B,1,F,T)
    const float* sig  = (const float*)d_in[1];   // input_sig    (B,1,N)
    const float* intf = (const float*)d_in[2];   // interference (B,1,N)

    unsigned short* Bt = (unsigned short*)d_ws;                 // 512 KB basis
    float* powp = (float*)((char*)d_ws + (size_t)8 * 512 * 64 * 2);

    hipLaunchKernelGGL(build_basis, dim3(512), dim3(256), 0, stream, Bt);
    hipMemsetAsync(d_out, 0, sizeof(float), stream);

    hipFuncSetAttribute((const void*)dft_gemm,
                        hipFuncAttributeMaxDynamicSharedMemorySize, LDS_TOTAL);
    dim3 gG(8, 64, 2);
    hipLaunchKernelGGL(dft_gemm, gG, dim3(256), LDS_TOTAL, stream,
                       sig, intf, Bt, powp);

    const double alpha_d = exp(-((double)256) / (16000.0 * 0.072));
    const float* noiseP = powp;                          // s=0: interference
    const float* noisyP = powp + (size_t)NFR * FPOW;     // s=1: input_sig
    dim3 gB((B_SZ * NCH * NF + 255) / 256);
    hipLaunchKernelGGL(spp_loss_kernel, gB, dim3(256), 0, stream,
                       noiseP, noisyP, est, (float*)d_out, (float)alpha_d);
}